// Round 6
// baseline (580.377 us; speedup 1.0000x reference)
//
#include <hip/hip_runtime.h>
#include <hip/hip_bf16.h>
#include <cstdint>
#include <cstddef>

// Problem dims
#define BB 4
#define LL 2048
#define EE 7
#define DD 512
#define HH 8
#define DHH 64
#define PP 720
#define NLAYER 2
#define UU 40
#define SCALE 0.125f
#define ROWS (BB*LL)                  // 8192
#define BIGN ((size_t)ROWS*DD)        // 4194304 elements per big buffer
#define NIN 21
#define FCH 256                       // flash keys per chunk
#define NCH (LL/FCH)                  // 8
#define PSTR 264                      // Ps row stride (u16)
#define VSTR 136                      // VsT row stride (u16)

typedef unsigned short u16;
typedef __bf16 bf16x8 __attribute__((ext_vector_type(8)));
typedef float  f32x4  __attribute__((ext_vector_type(4)));

__device__ __forceinline__ float bf2f(u16 u){
  union { uint32_t i; float f; } c; c.i = ((uint32_t)u) << 16; return c.f;
}
__device__ __forceinline__ u16 f2b(float f){
  __hip_bfloat16 h = __float2bfloat16(f);
  return *(u16*)&h;
}
__device__ __forceinline__ void gld_lds16(const u16* g, u16* l){
  __builtin_amdgcn_global_load_lds(
      (const __attribute__((address_space(1))) uint32_t*)g,
      (__attribute__((address_space(3))) uint32_t*)l, 16, 0, 0);
}

// ---------------- dtype probe: ln1_g[0] == 1.0 ----------------
__global__ void k_probe(const void* __restrict__ g, int* __restrict__ flag){
  if (threadIdx.x == 0 && blockIdx.x == 0){
    uint32_t bits = *(const uint32_t*)g;
    *flag = (bits == 0x3F800000u) ? 0 : 1;   // 1 = bf16 inputs
  }
}

#define NSMALL 15
struct ConvArgs { const void* src[NSMALL]; int off[NSMALL]; int n[NSMALL]; };

// ---------------- convert small inputs to fp32 staging ----------------
__global__ __launch_bounds__(256) void k_convert(ConvArgs a, float* __restrict__ dst,
    const int* __restrict__ flag){
  int id = blockIdx.y;
  int i = blockIdx.x*256 + threadIdx.x;
  if (i >= a.n[id]) return;
  float v;
  if (*flag) v = bf2f(((const u16*)a.src[id])[i]);
  else       v = ((const float*)a.src[id])[i];
  dst[(size_t)a.off[id] + i] = v;
}

// ---------------- weights -> bf16 W^T staging: dst[lay*6+mat][n][k] = W[lay][k][n] ----
struct WPtrs { const void* p[6]; };
__global__ __launch_bounds__(256) void k_wt(WPtrs wp, u16* __restrict__ dst,
    const int* __restrict__ flag){
  int mz = blockIdx.z; int lay = mz / 6, mat = mz % 6;
  int n0 = blockIdx.x*64, k0 = blockIdx.y*64;
  int t = threadIdx.x; int r = t >> 6, c = t & 63;
  __shared__ u16 tile[64][65];   // tile[k_local][n_local]
  int isbf = *flag;
  const void* src = wp.p[mat];
  for (int rr = r; rr < 64; rr += 4){
    size_t idx = ((size_t)lay*DD + (k0+rr))*DD + n0 + c;
    u16 v;
    if (isbf) v = ((const u16*)src)[idx];
    else      v = f2b(((const float*)src)[idx]);
    tile[rr][c] = v;
  }
  __syncthreads();
  u16* drow = dst + ((size_t)mz*DD + n0)*DD + k0;
  for (int rr = r; rr < 64; rr += 4)
    drow[(size_t)rr*DD + c] = tile[c][rr];
}

// ---------------- embed ----------------
__global__ __launch_bounds__(256) void k_embed(const float* __restrict__ x, const float* __restrict__ w,
    const float* __restrict__ b, float* __restrict__ h, u16* __restrict__ hB){
  int i = blockIdx.x*256 + threadIdx.x;
  int d = i & (DD-1); int r = i >> 9;
  const float* xr = x + r*EE;
  float acc = b[d];
  #pragma unroll
  for (int e=0;e<EE;e++) acc = fmaf(xr[e], w[e*DD+d], acc);
  h[i] = acc;
  hB[i] = f2b(acc);
}

// ---------------- zero ksum/vsum (4096 floats) ----------------
__global__ void k_zero(float* __restrict__ p){
  p[blockIdx.x*256 + threadIdx.x] = 0.f;
}

// ---------------- MFMA GEMM (generic): C = A(bf16) @ Bt^T + bias ----------------
__global__ __launch_bounds__(256) void k_gemm_mfma(const u16* __restrict__ A, const u16* __restrict__ Bt,
    const float* __restrict__ bias, float* __restrict__ Cf, u16* __restrict__ Cb, int relu){
  __shared__ u16 As[128*64];
  __shared__ u16 Bs[128*64];
  int t = threadIdx.x, wave = t >> 6, lane = t & 63;
  int mb = blockIdx.y * 128, nb = blockIdx.x * 128;
  int wm = (wave & 1) * 64, wn = (wave >> 1) * 64;
  f32x4 acc[4][4];
  #pragma unroll
  for (int i=0;i<4;i++)
    #pragma unroll
    for (int j=0;j<4;j++) acc[i][j] = (f32x4){0.f,0.f,0.f,0.f};

  int srow = wave*8 + (lane>>3);
  int scol = (lane&7)*8;
  const u16* Ag = A + (size_t)(mb + srow)*DD + scol;
  const u16* Bg = Bt + (size_t)(nb + srow)*DD + scol;

  for (int k0 = 0; k0 < DD; k0 += 64){
    __syncthreads();
    #pragma unroll
    for (int i=0;i<4;i++){
      gld_lds16(Ag + (size_t)i*32*DD + k0, As + (i*32 + wave*8)*64);
      gld_lds16(Bg + (size_t)i*32*DD + k0, Bs + (i*32 + wave*8)*64);
    }
    __syncthreads();
    #pragma unroll
    for (int ch=0; ch<2; ++ch){
      bf16x8 af[4], bf[4];
      int kof = ch*32 + (lane>>4)*8;
      #pragma unroll
      for (int i=0;i<4;i++) af[i] = *(const bf16x8*)(As + (wm + i*16 + (lane&15))*64 + kof);
      #pragma unroll
      for (int j=0;j<4;j++) bf[j] = *(const bf16x8*)(Bs + (wn + j*16 + (lane&15))*64 + kof);
      #pragma unroll
      for (int i=0;i<4;i++)
        #pragma unroll
        for (int j=0;j<4;j++)
          acc[i][j] = __builtin_amdgcn_mfma_f32_16x16x32_bf16(af[i], bf[j], acc[i][j], 0, 0, 0);
    }
  }
  #pragma unroll
  for (int i=0;i<4;i++){
    int rbase = mb + wm + i*16 + (lane>>4)*4;
    #pragma unroll
    for (int j=0;j<4;j++){
      int col = nb + wn + j*16 + (lane&15);
      float bv = bias[col];
      #pragma unroll
      for (int r=0;r<4;r++){
        float cv = acc[i][j][r] + bv;
        if (relu) cv = fmaxf(cv, 0.f);
        size_t off = (size_t)(rbase + r)*DD + col;
        if (Cf) Cf[off] = cv;
        if (Cb) Cb[off] = f2b(cv);
      }
    }
  }
}

// ---------------- fused QKV GEMM + ksum/vsum epilogue ----------------
__global__ __launch_bounds__(256) void k_gemm_qkv(const u16* __restrict__ A, const u16* __restrict__ Wt,
    const float* __restrict__ bq, const float* __restrict__ bk, const float* __restrict__ bv,
    u16* __restrict__ qB, u16* __restrict__ kB, u16* __restrict__ vB,
    float* __restrict__ ksum, float* __restrict__ vsum){
  __shared__ u16 As[128*64];
  __shared__ u16 Bs[128*64];
  int t = threadIdx.x, wave = t >> 6, lane = t & 63;
  int nbg = blockIdx.x * 128;
  int sel = nbg >> 9;
  int nb  = nbg & 511;
  int mb  = blockIdx.y * 128;
  const float* bias = (sel==0) ? bq : (sel==1) ? bk : bv;
  u16* out = (sel==0) ? qB : (sel==1) ? kB : vB;
  const u16* Bt = Wt + (size_t)sel*DD*DD;
  int wm = (wave & 1) * 64, wn = (wave >> 1) * 64;
  f32x4 acc[4][4];
  #pragma unroll
  for (int i=0;i<4;i++)
    #pragma unroll
    for (int j=0;j<4;j++) acc[i][j] = (f32x4){0.f,0.f,0.f,0.f};

  int srow = wave*8 + (lane>>3);
  int scol = (lane&7)*8;
  const u16* Ag = A + (size_t)(mb + srow)*DD + scol;
  const u16* Bg = Bt + (size_t)(nb + srow)*DD + scol;

  for (int k0 = 0; k0 < DD; k0 += 64){
    __syncthreads();
    #pragma unroll
    for (int i=0;i<4;i++){
      gld_lds16(Ag + (size_t)i*32*DD + k0, As + (i*32 + wave*8)*64);
      gld_lds16(Bg + (size_t)i*32*DD + k0, Bs + (i*32 + wave*8)*64);
    }
    __syncthreads();
    #pragma unroll
    for (int ch=0; ch<2; ++ch){
      bf16x8 af[4], bf[4];
      int kof = ch*32 + (lane>>4)*8;
      #pragma unroll
      for (int i=0;i<4;i++) af[i] = *(const bf16x8*)(As + (wm + i*16 + (lane&15))*64 + kof);
      #pragma unroll
      for (int j=0;j<4;j++) bf[j] = *(const bf16x8*)(Bs + (wn + j*16 + (lane&15))*64 + kof);
      #pragma unroll
      for (int i=0;i<4;i++)
        #pragma unroll
        for (int j=0;j<4;j++)
          acc[i][j] = __builtin_amdgcn_mfma_f32_16x16x32_bf16(af[i], bf[j], acc[i][j], 0, 0, 0);
    }
  }
  float csum[4] = {0.f,0.f,0.f,0.f};
  #pragma unroll
  for (int j=0;j<4;j++){
    int col = nb + wn + j*16 + (lane&15);
    float bvv = bias[col];
    #pragma unroll
    for (int i=0;i<4;i++){
      int rbase = mb + wm + i*16 + (lane>>4)*4;
      #pragma unroll
      for (int r=0;r<4;r++){
        float cv = acc[i][j][r] + bvv;
        out[(size_t)(rbase + r)*DD + col] = f2b(cv);
        csum[j] += cv;
      }
    }
  }
  if (sel > 0){
    float* dst = (sel==1) ? ksum : vsum;
    int bidx = mb >> 11;          // batch index (2048 rows per batch)
    #pragma unroll
    for (int j=0;j<4;j++){
      float v = csum[j];
      v += __shfl_xor(v, 16);
      v += __shfl_xor(v, 32);
      if ((lane>>4) == 0)
        atomicAdd(dst + bidx*512 + nb + wn + j*16 + lane, v);
    }
  }
}

// ---------------- MFMA sparsity: M[q] = SCALE*(max_k q.k - (q.ksum)/L) ----------------
__global__ __launch_bounds__(256) void k_sparsity_mfma(const u16* __restrict__ qB, const u16* __restrict__ kB,
    const float* __restrict__ ksum, float* __restrict__ Mout){
  int bh = blockIdx.y; int b = bh >> 3, hh = bh & 7;
  int q0 = blockIdx.x * 64;
  int t = threadIdx.x, wave = t >> 6, lane = t & 63;
  const u16* qbase = qB + ((size_t)(b*LL + q0))*DD + hh*DHH;
  const u16* kbase = kB + ((size_t)b*LL)*DD + hh*DHH;
  bf16x8 qa[4][2];
  #pragma unroll
  for (int i=0;i<4;i++)
    #pragma unroll
    for (int c=0;c<2;c++)
      qa[i][c] = *(const bf16x8*)(qbase + (size_t)(i*16 + (lane&15))*DD + c*32 + (lane>>4)*8);
  float rmax[4][4];
  #pragma unroll
  for (int i=0;i<4;i++)
    #pragma unroll
    for (int r=0;r<4;r++) rmax[i][r] = -3.0e38f;
  for (int kt = wave*16; kt < LL; kt += 64){
    bf16x8 kb0 = *(const bf16x8*)(kbase + (size_t)(kt + (lane&15))*DD + (lane>>4)*8);
    bf16x8 kb1 = *(const bf16x8*)(kbase + (size_t)(kt + (lane&15))*DD + 32 + (lane>>4)*8);
    #pragma unroll
    for (int i=0;i<4;i++){
      f32x4 a = (f32x4){0.f,0.f,0.f,0.f};
      a = __builtin_amdgcn_mfma_f32_16x16x32_bf16(qa[i][0], kb0, a, 0, 0, 0);
      a = __builtin_amdgcn_mfma_f32_16x16x32_bf16(qa[i][1], kb1, a, 0, 0, 0);
      #pragma unroll
      for (int r=0;r<4;r++) rmax[i][r] = fmaxf(rmax[i][r], a[r]);
    }
  }
  #pragma unroll
  for (int i=0;i<4;i++)
    #pragma unroll
    for (int r=0;r<4;r++){
      float v = rmax[i][r];
      v = fmaxf(v, __shfl_xor(v, 1));
      v = fmaxf(v, __shfl_xor(v, 2));
      v = fmaxf(v, __shfl_xor(v, 4));
      v = fmaxf(v, __shfl_xor(v, 8));
      rmax[i][r] = v;
    }
  __shared__ float smax[4][64];
  if ((lane & 15) == 0){
    #pragma unroll
    for (int i=0;i<4;i++)
      #pragma unroll
      for (int r=0;r<4;r++)
        smax[wave][i*16 + (lane>>4)*4 + r] = rmax[i][r];
  }
  __syncthreads();
  if (t < 64){
    float mx = fmaxf(fmaxf(smax[0][t], smax[1][t]), fmaxf(smax[2][t], smax[3][t]));
    const u16* qrow = qB + (size_t)(b*LL + q0 + t)*DD + hh*DHH;
    float dot = 0.f;
    #pragma unroll 16
    for (int d=0; d<DHH; ++d) dot += bf2f(qrow[d]) * ksum[bh*DHH + d];
    Mout[bh*LL + q0 + t] = SCALE * (mx - dot * (1.0f/LL));
  }
}

// ---------------- top-U: one wave per (b,h), registers only, lane-cached max ----------------
// Same semantics as np top_k: descending values, ties -> smaller index.
// __launch_bounds__(64,1): full VGPR budget so v[32] stays in registers (R5: spilled at VGPR=36).
__global__ __launch_bounds__(64, 1) void k_topk(const float* __restrict__ M, int* __restrict__ sidx){
  int bh = blockIdx.x; int lane = threadIdx.x;
  const float* src = M + (size_t)bh*LL + lane*32;
  float v[32];
  #pragma unroll
  for (int i=0;i<8;i++){
    float4 x4 = *(const float4*)(src + i*4);
    v[i*4+0]=x4.x; v[i*4+1]=x4.y; v[i*4+2]=x4.z; v[i*4+3]=x4.w;
  }
  // lane-local best (ascending scan, strict > : smallest index on ties)
  float lbest = -3.4e38f; int lidx = 0;
  #pragma unroll
  for (int i=0;i<32;i++) if (v[i] > lbest){ lbest = v[i]; lidx = i; }
  unsigned int taken = 0u;
  for (int it = 0; it < UU; ++it){
    float best = lbest; int bidx = lane*32 + lidx;
    #pragma unroll
    for (int off=1; off<64; off<<=1){
      float ov = __shfl_xor(best, off);
      int   oi = __shfl_xor(bidx, off);
      if (ov > best || (ov == best && oi < bidx)){ best = ov; bidx = oi; }
    }
    if (lane == 0) sidx[bh*UU + it] = bidx;
    if ((bidx >> 5) == lane){        // only the winning lane rescans its 32 values
      taken |= 1u << (bidx & 31);
      lbest = -3.4e38f; lidx = 0;
      #pragma unroll
      for (int i=0;i<32;i++){
        float vv = ((taken>>i)&1u) ? -3.4e38f : v[i];
        if (vv > lbest){ lbest = vv; lidx = i; }
      }
    }
  }
}

// ---------------- ctx default = vsum/L broadcast (bf16) ----------------
__global__ __launch_bounds__(256) void k_fill_ctx(const float* __restrict__ vsum, u16* __restrict__ ctxB){
  int i = blockIdx.x*256 + threadIdx.x;
  int c = i & (DD-1);
  int b = i >> 20;               // L*D = 2^20
  ctxB[i] = f2b(vsum[(b << 9) + c] * (1.0f/LL));
}

// ---------------- flash attention partial: per (bh, key-chunk) ----------------
__global__ __launch_bounds__(256) void k_flash(const u16* __restrict__ qB, const u16* __restrict__ kB,
    const u16* __restrict__ vB, const int* __restrict__ sidx,
    float* __restrict__ pO, float* __restrict__ pM, float* __restrict__ pS){
  int bh = blockIdx.y, c = blockIdx.x;
  int b = bh >> 3, hh = bh & 7;
  int t = threadIdx.x, w = t >> 6, lane = t & 63;
  int qlane = lane & 15, quad = lane >> 4;
  int l0 = c * FCH;
  __shared__ u16 Ps[48*PSTR];
  __shared__ u16 VsT[64*VSTR];
  __shared__ float wred[4][48];
  __shared__ float mrow[48];
  const u16* kbase = kB + (size_t)b*LL*DD + hh*DHH;
  const u16* vbase = vB + (size_t)b*LL*DD + hh*DHH;
  const u16* qbase = qB + (size_t)b*LL*DD + hh*DHH;

  bf16x8 qa[3][2];
  #pragma unroll
  for (int i=0;i<3;i++){
    int u = i*16 + qlane;
    if (u < UU){
      const u16* qr = qbase + (size_t)sidx[bh*UU + u]*DD + quad*8;
      qa[i][0] = *(const bf16x8*)qr;
      qa[i][1] = *(const bf16x8*)(qr + 32);
    } else {
      bf16x8 z;
      #pragma unroll
      for (int q8=0;q8<8;q8++) z[q8] = (__bf16)0.0f;
      qa[i][0] = z; qa[i][1] = z;
    }
  }
  f32x4 S[3][4];
  #pragma unroll
  for (int j=0;j<4;j++){
    const u16* kr = kbase + (size_t)(l0 + w*64 + j*16 + qlane)*DD + quad*8;
    bf16x8 k0 = *(const bf16x8*)kr;
    bf16x8 k1 = *(const bf16x8*)(kr + 32);
    #pragma unroll
    for (int i=0;i<3;i++){
      f32x4 a = (f32x4){0.f,0.f,0.f,0.f};
      a = __builtin_amdgcn_mfma_f32_16x16x32_bf16(qa[i][0], k0, a, 0, 0, 0);
      a = __builtin_amdgcn_mfma_f32_16x16x32_bf16(qa[i][1], k1, a, 0, 0, 0);
      S[i][j] = a;
    }
  }
  #pragma unroll
  for (int i=0;i<3;i++){
    #pragma unroll
    for (int r=0;r<4;r++){
      float m = -3.0e38f;
      #pragma unroll
      for (int j=0;j<4;j++){ S[i][j][r] *= SCALE; m = fmaxf(m, S[i][j][r]); }
      m = fmaxf(m, __shfl_xor(m, 1));
      m = fmaxf(m, __shfl_xor(m, 2));
      m = fmaxf(m, __shfl_xor(m, 4));
      m = fmaxf(m, __shfl_xor(m, 8));
      if (qlane == 0) wred[w][i*16 + quad*4 + r] = m;
    }
  }
  __syncthreads();
  if (t < 48) mrow[t] = fmaxf(fmaxf(wred[0][t], wred[1][t]), fmaxf(wred[2][t], wred[3][t]));
  __syncthreads();
  #pragma unroll
  for (int i=0;i<3;i++){
    #pragma unroll
    for (int r=0;r<4;r++){
      int row = i*16 + quad*4 + r;
      float m = mrow[row];
      float ls = 0.f;
      #pragma unroll
      for (int j=0;j<4;j++){
        float e = __expf(S[i][j][r] - m);
        ls += e;
        Ps[row*PSTR + w*64 + j*16 + qlane] = f2b(e);
      }
      ls += __shfl_xor(ls, 1);
      ls += __shfl_xor(ls, 2);
      ls += __shfl_xor(ls, 4);
      ls += __shfl_xor(ls, 8);
      if (qlane == 0) wred[w][row] = ls;
    }
  }
  __syncthreads();
  if (t < 48){
    pM[(bh*NCH + c)*48 + t] = mrow[t];
    pS[(bh*NCH + c)*48 + t] = wred[0][t] + wred[1][t] + wred[2][t] + wred[3][t];
  }
  f32x4 O[3];
  #pragma unroll
  for (int i=0;i<3;i++) O[i] = (f32x4){0.f,0.f,0.f,0.f};
  for (int half = 0; half < 2; ++half){
    __syncthreads();
    for (int idx = t; idx < 128*64; idx += 256){
      int rr = idx >> 6, d = idx & 63;
      VsT[d*VSTR + rr] = vbase[(size_t)(l0 + half*128 + rr)*DD + d];
    }
    __syncthreads();
    #pragma unroll
    for (int ks = 0; ks < 4; ++ks){
      int kloc = half*128 + ks*32;
      bf16x8 bfv = *(const bf16x8*)(VsT + (w*16 + qlane)*VSTR + ks*32 + quad*8);
      #pragma unroll
      for (int i=0;i<3;i++){
        bf16x8 af = *(const bf16x8*)(Ps + (i*16 + qlane)*PSTR + kloc + quad*8);
        O[i] = __builtin_amdgcn_mfma_f32_16x16x32_bf16(af, bfv, O[i], 0, 0, 0);
      }
    }
  }
  size_t ob = (size_t)(bh*NCH + c)*48*64;
  #pragma unroll
  for (int i=0;i<3;i++)
    #pragma unroll
    for (int r=0;r<4;r++)
      pO[ob + (size_t)(i*16 + quad*4 + r)*64 + w*16 + qlane] = O[i][r];
}

// ---------------- flash combine: merge chunk partials, scatter into ctxB ----------------
__global__ __launch_bounds__(256) void k_flash_red(const float* __restrict__ pO, const float* __restrict__ pM,
    const float* __restrict__ pS, const int* __restrict__ sidx, u16* __restrict__ ctxB){
  int bh = blockIdx.x; int b = bh >> 3, hh = bh & 7;
  int t = threadIdx.x;
  for (int idx = t; idx < UU*64; idx += 256){
    int u = idx >> 6, n = idx & 63;
    float m = -3.0e38f;
    #pragma unroll
    for (int c=0;c<NCH;c++) m = fmaxf(m, pM[(bh*NCH + c)*48 + u]);
    float s = 0.f, o = 0.f;
    #pragma unroll
    for (int c=0;c<NCH;c++){
      float wgt = __expf(pM[(bh*NCH + c)*48 + u] - m);
      s += wgt * pS[(bh*NCH + c)*48 + u];
      o += wgt * pO[((size_t)(bh*NCH + c)*48 + u)*64 + n];
    }
    int qrow = sidx[bh*UU + u];
    ctxB[(size_t)(b*LL + qrow)*DD + hh*DHH + n] = f2b(o / s);
  }
}

// ---------------- add+LN: one wave per row, shuffle reductions, no barriers ----------------
__global__ __launch_bounds__(256) void k_addln(const float* __restrict__ a, const float* __restrict__ r,
    const float* __restrict__ g, const float* __restrict__ bvec, float* __restrict__ out,
    u16* __restrict__ outB){
  int row = blockIdx.x*4 + (threadIdx.x >> 6);
  int lane = threadIdx.x & 63;
  size_t base = (size_t)row * DD + lane*8;
  float4 a0 = *(const float4*)(a + base);
  float4 a1 = *(const float4*)(a + base + 4);
  float4 r0 = *(const float4*)(r + base);
  float4 r1 = *(const float4*)(r + base + 4);
  float x[8] = {a0.x+r0.x, a0.y+r0.y, a0.z+r0.z, a0.w+r0.w,
                a1.x+r1.x, a1.y+r1.y, a1.z+r1.z, a1.w+r1.w};
  float s = 0.f;
  #pragma unroll
  for (int i=0;i<8;i++) s += x[i];
  #pragma unroll
  for (int off=1; off<64; off<<=1) s += __shfl_xor(s, off);
  float mean = s * (1.0f/DD);
  float vs = 0.f;
  #pragma unroll
  for (int i=0;i<8;i++){ x[i] -= mean; vs += x[i]*x[i]; }
  #pragma unroll
  for (int off=1; off<64; off<<=1) vs += __shfl_xor(vs, off);
  float rs = rsqrtf(vs * (1.0f/DD) + 1e-5f);
  const float* gp = g + lane*8;
  const float* bp = bvec + lane*8;
  float o[8];
  u16 ob[8];
  #pragma unroll
  for (int i=0;i<8;i++){ o[i] = x[i]*rs*gp[i] + bp[i]; ob[i] = f2b(o[i]); }
  *(float4*)(out + base)     = (float4){o[0],o[1],o[2],o[3]};
  *(float4*)(out + base + 4) = (float4){o[4],o[5],o[6],o[7]};
  *(ushort4*)(outB + base)     = (ushort4){ob[0],ob[1],ob[2],ob[3]};
  *(ushort4*)(outB + base + 4) = (ushort4){ob[4],ob[5],ob[6],ob[7]};
}

// ---------------- final projection ----------------
__global__ __launch_bounds__(64) void k_proj(const float* __restrict__ h, const float* __restrict__ pw,
    const float* __restrict__ pb, void* __restrict__ out, const int* __restrict__ flag){
  int rp = blockIdx.x; int b = rp / PP, pp = rp % PP;
  int t = threadIdx.x;
  const float* hr = h + (size_t)(b*LL + (LL-PP) + pp) * DD;
  float acc[EE];
  #pragma unroll
  for (int e=0;e<EE;e++) acc[e]=0.f;
  for (int d = t; d < DD; d += 64){
    float hv = hr[d];
    #pragma unroll
    for (int e=0;e<EE;e++) acc[e] = fmaf(hv, pw[d*EE+e], acc[e]);
  }
  int isbf = *flag;
  #pragma unroll
  for (int e=0;e<EE;e++){
    float rr = acc[e];
    for (int off=32; off>0; off>>=1) rr += __shfl_down(rr, off);
    if (t == 0){
      float val = rr + pb[e];
      if (isbf) ((__hip_bfloat16*)out)[(size_t)rp*EE + e] = __float2bfloat16(val);
      else      ((float*)out)[(size_t)rp*EE + e] = val;
    }
  }
}

extern "C" void kernel_launch(void* const* d_in, const int* in_sizes, int n_in,
                              void* d_out, int out_size, void* d_ws, size_t ws_size,
                              hipStream_t stream){
  float* ws    = (float*)d_ws;
  float* h     = ws;                                  // BIGN
  float* Mv    = ws + BIGN;                           // 65536
  float* ksum  = Mv + (size_t)BB*HH*LL;               // 2048
  float* vsum  = ksum + 2048;                         // 2048 (contiguous after ksum!)
  float* pM    = vsum + 2048;                         // 12288
  float* pS    = pM + 12288;                          // 12288
  float* pO    = pS + 12288;                          // 786432
  float* tmpF  = pO + 786432;                         // BIGN
  int*   sidx  = (int*)(tmpF + BIGN);                 // 1280
  int*   flag  = sidx + 1280;
  u16*   hB    = (u16*)(flag + 4);
  u16*   qB    = hB + BIGN;
  u16*   kB    = qB + BIGN;
  u16*   vB    = kB + BIGN;
  u16*   ctxB  = vB + BIGN;
  u16*   f1B   = ctxB + BIGN;
  u16*   wT    = f1B + BIGN;                          // 12*512*512 u16
  float* conv  = (float*)(wT + (size_t)12*DD*DD);

  static const int small_ids[NSMALL] = {0,1,2,4,6,8,10,12,14,15,16,17,18,19,20};
  ConvArgs ca;
  int off_all[NIN];
  int tot = 0, maxn = 0;
  for (int i = 0; i < NIN; ++i) off_all[i] = -1;
  for (int s = 0; s < NSMALL; ++s){
    int i = small_ids[s];
    ca.src[s] = d_in[i];
    ca.off[s] = tot;
    ca.n[s]   = in_sizes[i];
    off_all[i] = tot;
    tot += in_sizes[i];
    if (in_sizes[i] > maxn) maxn = in_sizes[i];
  }
  const float* x     = conv + off_all[0];
  const float* emb_w = conv + off_all[1];
  const float* emb_b = conv + off_all[2];
  const float* bq = conv + off_all[4];
  const float* bk = conv + off_all[6];
  const float* bv = conv + off_all[8];
  const float* bo = conv + off_all[10];
  const float* b1 = conv + off_all[12];
  const float* b2 = conv + off_all[14];
  const float* ln1g = conv + off_all[15]; const float* ln1b = conv + off_all[16];
  const float* ln2g = conv + off_all[17]; const float* ln2b = conv + off_all[18];
  const float* pw = conv + off_all[19]; const float* pb = conv + off_all[20];

  WPtrs wp;
  wp.p[0]=d_in[3]; wp.p[1]=d_in[5]; wp.p[2]=d_in[7];
  wp.p[3]=d_in[9]; wp.p[4]=d_in[11]; wp.p[5]=d_in[13];

  k_probe<<<1, 64, 0, stream>>>(d_in[15], flag);
  k_convert<<<dim3((maxn + 255)/256, NSMALL), 256, 0, stream>>>(ca, conv, flag);
  k_wt<<<dim3(8, 8, 12), 256, 0, stream>>>(wp, wT, flag);

  dim3 gg(DD/128, ROWS/128);     // (4,64)
  dim3 gq(3*DD/128, ROWS/128);   // (12,64) fused QKV

  k_embed<<<ROWS*DD/256, 256, 0, stream>>>(x, emb_w, emb_b, h, hB);
  for (int l = 0; l < NLAYER; ++l){
    const u16* WqkvT = wT + (size_t)(l*6 + 0)*DD*DD;
    const u16* WoT   = wT + (size_t)(l*6 + 3)*DD*DD;
    const u16* W1T   = wT + (size_t)(l*6 + 4)*DD*DD;
    const u16* W2T   = wT + (size_t)(l*6 + 5)*DD*DD;

    k_zero<<<16, 256, 0, stream>>>(ksum);
    k_gemm_qkv<<<gq, 256, 0, stream>>>(hB, WqkvT, bq + l*DD, bk + l*DD, bv + l*DD,
                                       qB, kB, vB, ksum, vsum);
    k_sparsity_mfma<<<dim3(LL/64, BB*HH), 256, 0, stream>>>(qB, kB, ksum, Mv);
    k_topk<<<BB*HH, 64, 0, stream>>>(Mv, sidx);
    k_fill_ctx<<<ROWS*DD/256, 256, 0, stream>>>(vsum, ctxB);
    k_flash<<<dim3(NCH, BB*HH), 256, 0, stream>>>(qB, kB, vB, sidx, pO, pM, pS);
    k_flash_red<<<BB*HH, 256, 0, stream>>>(pO, pM, pS, sidx, ctxB);
    k_gemm_mfma<<<gg, 256, 0, stream>>>(ctxB, WoT, bo + l*DD, tmpF, nullptr, 0);
    k_addln<<<ROWS/4, 256, 0, stream>>>(h, tmpF, ln1g + l*DD, ln1b + l*DD, h, hB);
    k_gemm_mfma<<<gg, 256, 0, stream>>>(hB, W1T, b1 + l*DD, nullptr, f1B, 1);
    k_gemm_mfma<<<gg, 256, 0, stream>>>(f1B, W2T, b2 + l*DD, tmpF, nullptr, 0);
    k_addln<<<ROWS/4, 256, 0, stream>>>(h, tmpF, ln2g + l*DD, ln2b + l*DD, h, hB);
  }
  k_proj<<<BB*PP, 64, 0, stream>>>(h, pw, pb, d_out, flag);
}

// Round 7
// 555.102 us; speedup vs baseline: 1.0455x; 1.0455x over previous
//
#include <hip/hip_runtime.h>
#include <hip/hip_bf16.h>
#include <cstdint>
#include <cstddef>

// Problem dims
#define BB 4
#define LL 2048
#define EE 7
#define DD 512
#define HH 8
#define DHH 64
#define PP 720
#define NLAYER 2
#define UU 40
#define SCALE 0.125f
#define ROWS (BB*LL)                  // 8192
#define BIGN ((size_t)ROWS*DD)        // 4194304 elements per big buffer
#define NIN 21
#define FCH 256                       // flash keys per chunk
#define NCH (LL/FCH)                  // 8
#define PSTR 264                      // Ps row stride (u16)
#define VSTR 136                      // VsT row stride (u16)

typedef unsigned short u16;
typedef __bf16 bf16x8 __attribute__((ext_vector_type(8)));
typedef float  f32x4  __attribute__((ext_vector_type(4)));

__device__ __forceinline__ float bf2f(u16 u){
  union { uint32_t i; float f; } c; c.i = ((uint32_t)u) << 16; return c.f;
}
__device__ __forceinline__ u16 f2b(float f){
  __hip_bfloat16 h = __float2bfloat16(f);
  return *(u16*)&h;
}
__device__ __forceinline__ void gld_lds16(const u16* g, u16* l){
  __builtin_amdgcn_global_load_lds(
      (const __attribute__((address_space(1))) uint32_t*)g,
      (__attribute__((address_space(3))) uint32_t*)l, 16, 0, 0);
}

// ---------------- dtype probe: ln1_g[0] == 1.0 ----------------
__global__ void k_probe(const void* __restrict__ g, int* __restrict__ flag){
  if (threadIdx.x == 0 && blockIdx.x == 0){
    uint32_t bits = *(const uint32_t*)g;
    *flag = (bits == 0x3F800000u) ? 0 : 1;   // 1 = bf16 inputs
  }
}

#define NSMALL 15
struct ConvArgs { const void* src[NSMALL]; int off[NSMALL]; int n[NSMALL]; };

// ---------------- convert small inputs to fp32 staging ----------------
__global__ __launch_bounds__(256) void k_convert(ConvArgs a, float* __restrict__ dst,
    const int* __restrict__ flag){
  int id = blockIdx.y;
  int i = blockIdx.x*256 + threadIdx.x;
  if (i >= a.n[id]) return;
  float v;
  if (*flag) v = bf2f(((const u16*)a.src[id])[i]);
  else       v = ((const float*)a.src[id])[i];
  dst[(size_t)a.off[id] + i] = v;
}

// ---------------- weights -> bf16 W^T staging: dst[lay*6+mat][n][k] = W[lay][k][n] ----
struct WPtrs { const void* p[6]; };
__global__ __launch_bounds__(256) void k_wt(WPtrs wp, u16* __restrict__ dst,
    const int* __restrict__ flag){
  int mz = blockIdx.z; int lay = mz / 6, mat = mz % 6;
  int n0 = blockIdx.x*64, k0 = blockIdx.y*64;
  int t = threadIdx.x; int r = t >> 6, c = t & 63;
  __shared__ u16 tile[64][65];   // tile[k_local][n_local]
  int isbf = *flag;
  const void* src = wp.p[mat];
  for (int rr = r; rr < 64; rr += 4){
    size_t idx = ((size_t)lay*DD + (k0+rr))*DD + n0 + c;
    u16 v;
    if (isbf) v = ((const u16*)src)[idx];
    else      v = f2b(((const float*)src)[idx]);
    tile[rr][c] = v;
  }
  __syncthreads();
  u16* drow = dst + ((size_t)mz*DD + n0)*DD + k0;
  for (int rr = r; rr < 64; rr += 4)
    drow[(size_t)rr*DD + c] = tile[c][rr];
}

// ---------------- embed ----------------
__global__ __launch_bounds__(256) void k_embed(const float* __restrict__ x, const float* __restrict__ w,
    const float* __restrict__ b, float* __restrict__ h, u16* __restrict__ hB){
  int i = blockIdx.x*256 + threadIdx.x;
  int d = i & (DD-1); int r = i >> 9;
  const float* xr = x + r*EE;
  float acc = b[d];
  #pragma unroll
  for (int e=0;e<EE;e++) acc = fmaf(xr[e], w[e*DD+d], acc);
  h[i] = acc;
  hB[i] = f2b(acc);
}

// ---------------- zero ksum/vsum (4096 floats) ----------------
__global__ void k_zero(float* __restrict__ p){
  p[blockIdx.x*256 + threadIdx.x] = 0.f;
}

// ---------------- MFMA GEMM (generic): C = A(bf16) @ Bt^T + bias ----------------
__global__ __launch_bounds__(256) void k_gemm_mfma(const u16* __restrict__ A, const u16* __restrict__ Bt,
    const float* __restrict__ bias, float* __restrict__ Cf, u16* __restrict__ Cb, int relu){
  __shared__ u16 As[128*64];
  __shared__ u16 Bs[128*64];
  int t = threadIdx.x, wave = t >> 6, lane = t & 63;
  int mb = blockIdx.y * 128, nb = blockIdx.x * 128;
  int wm = (wave & 1) * 64, wn = (wave >> 1) * 64;
  f32x4 acc[4][4];
  #pragma unroll
  for (int i=0;i<4;i++)
    #pragma unroll
    for (int j=0;j<4;j++) acc[i][j] = (f32x4){0.f,0.f,0.f,0.f};

  int srow = wave*8 + (lane>>3);
  int scol = (lane&7)*8;
  const u16* Ag = A + (size_t)(mb + srow)*DD + scol;
  const u16* Bg = Bt + (size_t)(nb + srow)*DD + scol;

  for (int k0 = 0; k0 < DD; k0 += 64){
    __syncthreads();
    #pragma unroll
    for (int i=0;i<4;i++){
      gld_lds16(Ag + (size_t)i*32*DD + k0, As + (i*32 + wave*8)*64);
      gld_lds16(Bg + (size_t)i*32*DD + k0, Bs + (i*32 + wave*8)*64);
    }
    __syncthreads();
    #pragma unroll
    for (int ch=0; ch<2; ++ch){
      bf16x8 af[4], bf[4];
      int kof = ch*32 + (lane>>4)*8;
      #pragma unroll
      for (int i=0;i<4;i++) af[i] = *(const bf16x8*)(As + (wm + i*16 + (lane&15))*64 + kof);
      #pragma unroll
      for (int j=0;j<4;j++) bf[j] = *(const bf16x8*)(Bs + (wn + j*16 + (lane&15))*64 + kof);
      #pragma unroll
      for (int i=0;i<4;i++)
        #pragma unroll
        for (int j=0;j<4;j++)
          acc[i][j] = __builtin_amdgcn_mfma_f32_16x16x32_bf16(af[i], bf[j], acc[i][j], 0, 0, 0);
    }
  }
  #pragma unroll
  for (int i=0;i<4;i++){
    int rbase = mb + wm + i*16 + (lane>>4)*4;
    #pragma unroll
    for (int j=0;j<4;j++){
      int col = nb + wn + j*16 + (lane&15);
      float bv = bias[col];
      #pragma unroll
      for (int r=0;r<4;r++){
        float cv = acc[i][j][r] + bv;
        if (relu) cv = fmaxf(cv, 0.f);
        size_t off = (size_t)(rbase + r)*DD + col;
        if (Cf) Cf[off] = cv;
        if (Cb) Cb[off] = f2b(cv);
      }
    }
  }
}

// ---------------- fused QKV GEMM + ksum/vsum epilogue ----------------
__global__ __launch_bounds__(256) void k_gemm_qkv(const u16* __restrict__ A, const u16* __restrict__ Wt,
    const float* __restrict__ bq, const float* __restrict__ bk, const float* __restrict__ bv,
    u16* __restrict__ qB, u16* __restrict__ kB, u16* __restrict__ vB,
    float* __restrict__ ksum, float* __restrict__ vsum){
  __shared__ u16 As[128*64];
  __shared__ u16 Bs[128*64];
  int t = threadIdx.x, wave = t >> 6, lane = t & 63;
  int nbg = blockIdx.x * 128;
  int sel = nbg >> 9;
  int nb  = nbg & 511;
  int mb  = blockIdx.y * 128;
  const float* bias = (sel==0) ? bq : (sel==1) ? bk : bv;
  u16* out = (sel==0) ? qB : (sel==1) ? kB : vB;
  const u16* Bt = Wt + (size_t)sel*DD*DD;
  int wm = (wave & 1) * 64, wn = (wave >> 1) * 64;
  f32x4 acc[4][4];
  #pragma unroll
  for (int i=0;i<4;i++)
    #pragma unroll
    for (int j=0;j<4;j++) acc[i][j] = (f32x4){0.f,0.f,0.f,0.f};

  int srow = wave*8 + (lane>>3);
  int scol = (lane&7)*8;
  const u16* Ag = A + (size_t)(mb + srow)*DD + scol;
  const u16* Bg = Bt + (size_t)(nb + srow)*DD + scol;

  for (int k0 = 0; k0 < DD; k0 += 64){
    __syncthreads();
    #pragma unroll
    for (int i=0;i<4;i++){
      gld_lds16(Ag + (size_t)i*32*DD + k0, As + (i*32 + wave*8)*64);
      gld_lds16(Bg + (size_t)i*32*DD + k0, Bs + (i*32 + wave*8)*64);
    }
    __syncthreads();
    #pragma unroll
    for (int ch=0; ch<2; ++ch){
      bf16x8 af[4], bf[4];
      int kof = ch*32 + (lane>>4)*8;
      #pragma unroll
      for (int i=0;i<4;i++) af[i] = *(const bf16x8*)(As + (wm + i*16 + (lane&15))*64 + kof);
      #pragma unroll
      for (int j=0;j<4;j++) bf[j] = *(const bf16x8*)(Bs + (wn + j*16 + (lane&15))*64 + kof);
      #pragma unroll
      for (int i=0;i<4;i++)
        #pragma unroll
        for (int j=0;j<4;j++)
          acc[i][j] = __builtin_amdgcn_mfma_f32_16x16x32_bf16(af[i], bf[j], acc[i][j], 0, 0, 0);
    }
  }
  float csum[4] = {0.f,0.f,0.f,0.f};
  #pragma unroll
  for (int j=0;j<4;j++){
    int col = nb + wn + j*16 + (lane&15);
    float bvv = bias[col];
    #pragma unroll
    for (int i=0;i<4;i++){
      int rbase = mb + wm + i*16 + (lane>>4)*4;
      #pragma unroll
      for (int r=0;r<4;r++){
        float cv = acc[i][j][r] + bvv;
        out[(size_t)(rbase + r)*DD + col] = f2b(cv);
        csum[j] += cv;
      }
    }
  }
  if (sel > 0){
    float* dst = (sel==1) ? ksum : vsum;
    int bidx = mb >> 11;          // batch index (2048 rows per batch)
    #pragma unroll
    for (int j=0;j<4;j++){
      float v = csum[j];
      v += __shfl_xor(v, 16);
      v += __shfl_xor(v, 32);
      if ((lane>>4) == 0)
        atomicAdd(dst + bidx*512 + nb + wn + j*16 + lane, v);
    }
  }
}

// ---------------- MFMA sparsity: M[q] = SCALE*(max_k q.k - (q.ksum)/L) ----------------
__global__ __launch_bounds__(256) void k_sparsity_mfma(const u16* __restrict__ qB, const u16* __restrict__ kB,
    const float* __restrict__ ksum, float* __restrict__ Mout){
  int bh = blockIdx.y; int b = bh >> 3, hh = bh & 7;
  int q0 = blockIdx.x * 64;
  int t = threadIdx.x, wave = t >> 6, lane = t & 63;
  const u16* qbase = qB + ((size_t)(b*LL + q0))*DD + hh*DHH;
  const u16* kbase = kB + ((size_t)b*LL)*DD + hh*DHH;
  bf16x8 qa[4][2];
  #pragma unroll
  for (int i=0;i<4;i++)
    #pragma unroll
    for (int c=0;c<2;c++)
      qa[i][c] = *(const bf16x8*)(qbase + (size_t)(i*16 + (lane&15))*DD + c*32 + (lane>>4)*8);
  float rmax[4][4];
  #pragma unroll
  for (int i=0;i<4;i++)
    #pragma unroll
    for (int r=0;r<4;r++) rmax[i][r] = -3.0e38f;
  for (int kt = wave*16; kt < LL; kt += 64){
    bf16x8 kb0 = *(const bf16x8*)(kbase + (size_t)(kt + (lane&15))*DD + (lane>>4)*8);
    bf16x8 kb1 = *(const bf16x8*)(kbase + (size_t)(kt + (lane&15))*DD + 32 + (lane>>4)*8);
    #pragma unroll
    for (int i=0;i<4;i++){
      f32x4 a = (f32x4){0.f,0.f,0.f,0.f};
      a = __builtin_amdgcn_mfma_f32_16x16x32_bf16(qa[i][0], kb0, a, 0, 0, 0);
      a = __builtin_amdgcn_mfma_f32_16x16x32_bf16(qa[i][1], kb1, a, 0, 0, 0);
      #pragma unroll
      for (int r=0;r<4;r++) rmax[i][r] = fmaxf(rmax[i][r], a[r]);
    }
  }
  #pragma unroll
  for (int i=0;i<4;i++)
    #pragma unroll
    for (int r=0;r<4;r++){
      float v = rmax[i][r];
      v = fmaxf(v, __shfl_xor(v, 1));
      v = fmaxf(v, __shfl_xor(v, 2));
      v = fmaxf(v, __shfl_xor(v, 4));
      v = fmaxf(v, __shfl_xor(v, 8));
      rmax[i][r] = v;
    }
  __shared__ float smax[4][64];
  if ((lane & 15) == 0){
    #pragma unroll
    for (int i=0;i<4;i++)
      #pragma unroll
      for (int r=0;r<4;r++)
        smax[wave][i*16 + (lane>>4)*4 + r] = rmax[i][r];
  }
  __syncthreads();
  if (t < 64){
    float mx = fmaxf(fmaxf(smax[0][t], smax[1][t]), fmaxf(smax[2][t], smax[3][t]));
    const u16* qrow = qB + (size_t)(b*LL + q0 + t)*DD + hh*DHH;
    float dot = 0.f;
    #pragma unroll 16
    for (int d=0; d<DHH; ++d) dot += bf2f(qrow[d]) * ksum[bh*DHH + d];
    Mout[bh*LL + q0 + t] = SCALE * (mx - dot * (1.0f/LL));
  }
}

// ---------------- top-U: one wave per (b,h), values in LDS (no private arrays!) ----------------
// R5/R6 lesson: LLVM spills private v[32] to scratch no matter the VGPR budget.
// LDS interleaved mapping idx = lane + i*64 -> bank = lane%32, conflict-free.
// np semantics: descending values, ties -> smaller index (lane-local ascending scan
// with strict >, cross-lane butterfly with explicit smaller-index tie-break).
__global__ __launch_bounds__(64) void k_topk(const float* __restrict__ M, int* __restrict__ sidx){
  int bh = blockIdx.x; int lane = threadIdx.x;
  __shared__ float vals[LL];   // 8 KB
  const float* src = M + (size_t)bh*LL;
  #pragma unroll
  for (int j = 0; j < 8; ++j){
    float4 x4 = *(const float4*)(src + j*256 + lane*4);
    *(float4*)(vals + j*256 + lane*4) = x4;
  }
  __syncthreads();
  for (int it = 0; it < UU; ++it){
    float best = -3.4e38f; int bidx = lane;
    #pragma unroll
    for (int i = 0; i < 32; ++i){
      float v = vals[lane + i*64];
      if (v > best){ best = v; bidx = lane + i*64; }
    }
    #pragma unroll
    for (int off=1; off<64; off<<=1){
      float ov = __shfl_xor(best, off);
      int   oi = __shfl_xor(bidx, off);
      if (ov > best || (ov == best && oi < bidx)){ best = ov; bidx = oi; }
    }
    if (lane == 0) sidx[bh*UU + it] = bidx;
    if ((bidx & 63) == lane) vals[bidx] = -3.4e38f;
    __syncthreads();
  }
}

// ---------------- ctx default = vsum/L broadcast (bf16) ----------------
__global__ __launch_bounds__(256) void k_fill_ctx(const float* __restrict__ vsum, u16* __restrict__ ctxB){
  int i = blockIdx.x*256 + threadIdx.x;
  int c = i & (DD-1);
  int b = i >> 20;               // L*D = 2^20
  ctxB[i] = f2b(vsum[(b << 9) + c] * (1.0f/LL));
}

// ---------------- flash attention partial: per (bh, key-chunk) ----------------
__global__ __launch_bounds__(256) void k_flash(const u16* __restrict__ qB, const u16* __restrict__ kB,
    const u16* __restrict__ vB, const int* __restrict__ sidx,
    float* __restrict__ pO, float* __restrict__ pM, float* __restrict__ pS){
  int bh = blockIdx.y, c = blockIdx.x;
  int b = bh >> 3, hh = bh & 7;
  int t = threadIdx.x, w = t >> 6, lane = t & 63;
  int qlane = lane & 15, quad = lane >> 4;
  int l0 = c * FCH;
  __shared__ u16 Ps[48*PSTR];
  __shared__ u16 VsT[64*VSTR];
  __shared__ float wred[4][48];
  __shared__ float mrow[48];
  const u16* kbase = kB + (size_t)b*LL*DD + hh*DHH;
  const u16* vbase = vB + (size_t)b*LL*DD + hh*DHH;
  const u16* qbase = qB + (size_t)b*LL*DD + hh*DHH;

  bf16x8 qa[3][2];
  #pragma unroll
  for (int i=0;i<3;i++){
    int u = i*16 + qlane;
    if (u < UU){
      const u16* qr = qbase + (size_t)sidx[bh*UU + u]*DD + quad*8;
      qa[i][0] = *(const bf16x8*)qr;
      qa[i][1] = *(const bf16x8*)(qr + 32);
    } else {
      bf16x8 z;
      #pragma unroll
      for (int q8=0;q8<8;q8++) z[q8] = (__bf16)0.0f;
      qa[i][0] = z; qa[i][1] = z;
    }
  }
  f32x4 S[3][4];
  #pragma unroll
  for (int j=0;j<4;j++){
    const u16* kr = kbase + (size_t)(l0 + w*64 + j*16 + qlane)*DD + quad*8;
    bf16x8 k0 = *(const bf16x8*)kr;
    bf16x8 k1 = *(const bf16x8*)(kr + 32);
    #pragma unroll
    for (int i=0;i<3;i++){
      f32x4 a = (f32x4){0.f,0.f,0.f,0.f};
      a = __builtin_amdgcn_mfma_f32_16x16x32_bf16(qa[i][0], k0, a, 0, 0, 0);
      a = __builtin_amdgcn_mfma_f32_16x16x32_bf16(qa[i][1], k1, a, 0, 0, 0);
      S[i][j] = a;
    }
  }
  #pragma unroll
  for (int i=0;i<3;i++){
    #pragma unroll
    for (int r=0;r<4;r++){
      float m = -3.0e38f;
      #pragma unroll
      for (int j=0;j<4;j++){ S[i][j][r] *= SCALE; m = fmaxf(m, S[i][j][r]); }
      m = fmaxf(m, __shfl_xor(m, 1));
      m = fmaxf(m, __shfl_xor(m, 2));
      m = fmaxf(m, __shfl_xor(m, 4));
      m = fmaxf(m, __shfl_xor(m, 8));
      if (qlane == 0) wred[w][i*16 + quad*4 + r] = m;
    }
  }
  __syncthreads();
  if (t < 48) mrow[t] = fmaxf(fmaxf(wred[0][t], wred[1][t]), fmaxf(wred[2][t], wred[3][t]));
  __syncthreads();
  #pragma unroll
  for (int i=0;i<3;i++){
    #pragma unroll
    for (int r=0;r<4;r++){
      int row = i*16 + quad*4 + r;
      float m = mrow[row];
      float ls = 0.f;
      #pragma unroll
      for (int j=0;j<4;j++){
        float e = __expf(S[i][j][r] - m);
        ls += e;
        Ps[row*PSTR + w*64 + j*16 + qlane] = f2b(e);
      }
      ls += __shfl_xor(ls, 1);
      ls += __shfl_xor(ls, 2);
      ls += __shfl_xor(ls, 4);
      ls += __shfl_xor(ls, 8);
      if (qlane == 0) wred[w][row] = ls;
    }
  }
  __syncthreads();
  if (t < 48){
    pM[(bh*NCH + c)*48 + t] = mrow[t];
    pS[(bh*NCH + c)*48 + t] = wred[0][t] + wred[1][t] + wred[2][t] + wred[3][t];
  }
  f32x4 O[3];
  #pragma unroll
  for (int i=0;i<3;i++) O[i] = (f32x4){0.f,0.f,0.f,0.f};
  for (int half = 0; half < 2; ++half){
    __syncthreads();
    for (int idx = t; idx < 128*64; idx += 256){
      int rr = idx >> 6, d = idx & 63;
      VsT[d*VSTR + rr] = vbase[(size_t)(l0 + half*128 + rr)*DD + d];
    }
    __syncthreads();
    #pragma unroll
    for (int ks = 0; ks < 4; ++ks){
      int kloc = half*128 + ks*32;
      bf16x8 bfv = *(const bf16x8*)(VsT + (w*16 + qlane)*VSTR + ks*32 + quad*8);
      #pragma unroll
      for (int i=0;i<3;i++){
        bf16x8 af = *(const bf16x8*)(Ps + (i*16 + qlane)*PSTR + kloc + quad*8);
        O[i] = __builtin_amdgcn_mfma_f32_16x16x32_bf16(af, bfv, O[i], 0, 0, 0);
      }
    }
  }
  size_t ob = (size_t)(bh*NCH + c)*48*64;
  #pragma unroll
  for (int i=0;i<3;i++)
    #pragma unroll
    for (int r=0;r<4;r++)
      pO[ob + (size_t)(i*16 + quad*4 + r)*64 + w*16 + qlane] = O[i][r];
}

// ---------------- flash combine: merge chunk partials, scatter into ctxB ----------------
__global__ __launch_bounds__(256) void k_flash_red(const float* __restrict__ pO, const float* __restrict__ pM,
    const float* __restrict__ pS, const int* __restrict__ sidx, u16* __restrict__ ctxB){
  int bh = blockIdx.x; int b = bh >> 3, hh = bh & 7;
  int t = threadIdx.x;
  for (int idx = t; idx < UU*64; idx += 256){
    int u = idx >> 6, n = idx & 63;
    float m = -3.0e38f;
    #pragma unroll
    for (int c=0;c<NCH;c++) m = fmaxf(m, pM[(bh*NCH + c)*48 + u]);
    float s = 0.f, o = 0.f;
    #pragma unroll
    for (int c=0;c<NCH;c++){
      float wgt = __expf(pM[(bh*NCH + c)*48 + u] - m);
      s += wgt * pS[(bh*NCH + c)*48 + u];
      o += wgt * pO[((size_t)(bh*NCH + c)*48 + u)*64 + n];
    }
    int qrow = sidx[bh*UU + u];
    ctxB[(size_t)(b*LL + qrow)*DD + hh*DHH + n] = f2b(o / s);
  }
}

// ---------------- add+LN: one wave per row, shuffle reductions, no barriers ----------------
__global__ __launch_bounds__(256) void k_addln(const float* __restrict__ a, const float* __restrict__ r,
    const float* __restrict__ g, const float* __restrict__ bvec, float* __restrict__ out,
    u16* __restrict__ outB){
  int row = blockIdx.x*4 + (threadIdx.x >> 6);
  int lane = threadIdx.x & 63;
  size_t base = (size_t)row * DD + lane*8;
  float4 a0 = *(const float4*)(a + base);
  float4 a1 = *(const float4*)(a + base + 4);
  float4 r0 = *(const float4*)(r + base);
  float4 r1 = *(const float4*)(r + base + 4);
  float x[8] = {a0.x+r0.x, a0.y+r0.y, a0.z+r0.z, a0.w+r0.w,
                a1.x+r1.x, a1.y+r1.y, a1.z+r1.z, a1.w+r1.w};
  float s = 0.f;
  #pragma unroll
  for (int i=0;i<8;i++) s += x[i];
  #pragma unroll
  for (int off=1; off<64; off<<=1) s += __shfl_xor(s, off);
  float mean = s * (1.0f/DD);
  float vs = 0.f;
  #pragma unroll
  for (int i=0;i<8;i++){ x[i] -= mean; vs += x[i]*x[i]; }
  #pragma unroll
  for (int off=1; off<64; off<<=1) vs += __shfl_xor(vs, off);
  float rs = rsqrtf(vs * (1.0f/DD) + 1e-5f);
  const float* gp = g + lane*8;
  const float* bp = bvec + lane*8;
  float o[8];
  u16 ob[8];
  #pragma unroll
  for (int i=0;i<8;i++){ o[i] = x[i]*rs*gp[i] + bp[i]; ob[i] = f2b(o[i]); }
  *(float4*)(out + base)     = (float4){o[0],o[1],o[2],o[3]};
  *(float4*)(out + base + 4) = (float4){o[4],o[5],o[6],o[7]};
  *(ushort4*)(outB + base)     = (ushort4){ob[0],ob[1],ob[2],ob[3]};
  *(ushort4*)(outB + base + 4) = (ushort4){ob[4],ob[5],ob[6],ob[7]};
}

// ---------------- final projection ----------------
__global__ __launch_bounds__(64) void k_proj(const float* __restrict__ h, const float* __restrict__ pw,
    const float* __restrict__ pb, void* __restrict__ out, const int* __restrict__ flag){
  int rp = blockIdx.x; int b = rp / PP, pp = rp % PP;
  int t = threadIdx.x;
  const float* hr = h + (size_t)(b*LL + (LL-PP) + pp) * DD;
  float acc[EE];
  #pragma unroll
  for (int e=0;e<EE;e++) acc[e]=0.f;
  for (int d = t; d < DD; d += 64){
    float hv = hr[d];
    #pragma unroll
    for (int e=0;e<EE;e++) acc[e] = fmaf(hv, pw[d*EE+e], acc[e]);
  }
  int isbf = *flag;
  #pragma unroll
  for (int e=0;e<EE;e++){
    float rr = acc[e];
    for (int off=32; off>0; off>>=1) rr += __shfl_down(rr, off);
    if (t == 0){
      float val = rr + pb[e];
      if (isbf) ((__hip_bfloat16*)out)[(size_t)rp*EE + e] = __float2bfloat16(val);
      else      ((float*)out)[(size_t)rp*EE + e] = val;
    }
  }
}

extern "C" void kernel_launch(void* const* d_in, const int* in_sizes, int n_in,
                              void* d_out, int out_size, void* d_ws, size_t ws_size,
                              hipStream_t stream){
  float* ws    = (float*)d_ws;
  float* h     = ws;                                  // BIGN
  float* Mv    = ws + BIGN;                           // 65536
  float* ksum  = Mv + (size_t)BB*HH*LL;               // 2048
  float* vsum  = ksum + 2048;                         // 2048 (contiguous after ksum!)
  float* pM    = vsum + 2048;                         // 12288
  float* pS    = pM + 12288;                          // 12288
  float* pO    = pS + 12288;                          // 786432
  float* tmpF  = pO + 786432;                         // BIGN
  int*   sidx  = (int*)(tmpF + BIGN);                 // 1280
  int*   flag  = sidx + 1280;
  u16*   hB    = (u16*)(flag + 4);
  u16*   qB    = hB + BIGN;
  u16*   kB    = qB + BIGN;
  u16*   vB    = kB + BIGN;
  u16*   ctxB  = vB + BIGN;
  u16*   f1B   = ctxB + BIGN;
  u16*   wT    = f1B + BIGN;                          // 12*512*512 u16
  float* conv  = (float*)(wT + (size_t)12*DD*DD);

  static const int small_ids[NSMALL] = {0,1,2,4,6,8,10,12,14,15,16,17,18,19,20};
  ConvArgs ca;
  int off_all[NIN];
  int tot = 0, maxn = 0;
  for (int i = 0; i < NIN; ++i) off_all[i] = -1;
  for (int s = 0; s < NSMALL; ++s){
    int i = small_ids[s];
    ca.src[s] = d_in[i];
    ca.off[s] = tot;
    ca.n[s]   = in_sizes[i];
    off_all[i] = tot;
    tot += in_sizes[i];
    if (in_sizes[i] > maxn) maxn = in_sizes[i];
  }
  const float* x     = conv + off_all[0];
  const float* emb_w = conv + off_all[1];
  const float* emb_b = conv + off_all[2];
  const float* bq = conv + off_all[4];
  const float* bk = conv + off_all[6];
  const float* bv = conv + off_all[8];
  const float* bo = conv + off_all[10];
  const float* b1 = conv + off_all[12];
  const float* b2 = conv + off_all[14];
  const float* ln1g = conv + off_all[15]; const float* ln1b = conv + off_all[16];
  const float* ln2g = conv + off_all[17]; const float* ln2b = conv + off_all[18];
  const float* pw = conv + off_all[19]; const float* pb = conv + off_all[20];

  WPtrs wp;
  wp.p[0]=d_in[3]; wp.p[1]=d_in[5]; wp.p[2]=d_in[7];
  wp.p[3]=d_in[9]; wp.p[4]=d_in[11]; wp.p[5]=d_in[13];

  k_probe<<<1, 64, 0, stream>>>(d_in[15], flag);
  k_convert<<<dim3((maxn + 255)/256, NSMALL), 256, 0, stream>>>(ca, conv, flag);
  k_wt<<<dim3(8, 8, 12), 256, 0, stream>>>(wp, wT, flag);

  dim3 gg(DD/128, ROWS/128);     // (4,64)
  dim3 gq(3*DD/128, ROWS/128);   // (12,64) fused QKV

  k_embed<<<ROWS*DD/256, 256, 0, stream>>>(x, emb_w, emb_b, h, hB);
  for (int l = 0; l < NLAYER; ++l){
    const u16* WqkvT = wT + (size_t)(l*6 + 0)*DD*DD;
    const u16* WoT   = wT + (size_t)(l*6 + 3)*DD*DD;
    const u16* W1T   = wT + (size_t)(l*6 + 4)*DD*DD;
    const u16* W2T   = wT + (size_t)(l*6 + 5)*DD*DD;

    k_zero<<<16, 256, 0, stream>>>(ksum);
    k_gemm_qkv<<<gq, 256, 0, stream>>>(hB, WqkvT, bq + l*DD, bk + l*DD, bv + l*DD,
                                       qB, kB, vB, ksum, vsum);
    k_sparsity_mfma<<<dim3(LL/64, BB*HH), 256, 0, stream>>>(qB, kB, ksum, Mv);
    k_topk<<<BB*HH, 64, 0, stream>>>(Mv, sidx);
    k_fill_ctx<<<ROWS*DD/256, 256, 0, stream>>>(vsum, ctxB);
    k_flash<<<dim3(NCH, BB*HH), 256, 0, stream>>>(qB, kB, vB, sidx, pO, pM, pS);
    k_flash_red<<<BB*HH, 256, 0, stream>>>(pO, pM, pS, sidx, ctxB);
    k_gemm_mfma<<<gg, 256, 0, stream>>>(ctxB, WoT, bo + l*DD, tmpF, nullptr, 0);
    k_addln<<<ROWS/4, 256, 0, stream>>>(h, tmpF, ln1g + l*DD, ln1b + l*DD, h, hB);
    k_gemm_mfma<<<gg, 256, 0, stream>>>(hB, W1T, b1 + l*DD, nullptr, f1B, 1);
    k_gemm_mfma<<<gg, 256, 0, stream>>>(f1B, W2T, b2 + l*DD, tmpF, nullptr, 0);
    k_addln<<<ROWS/4, 256, 0, stream>>>(h, tmpF, ln2g + l*DD, ln2b + l*DD, h, hB);
  }
  k_proj<<<BB*PP, 64, 0, stream>>>(h, pw, pb, d_out, flag);
}